// Round 1
// baseline (9259.765 us; speedup 1.0000x reference)
//
#include <hip/hip_runtime.h>
#include <hip/hip_bf16.h>

// Problem constants
#define B_    2
#define S_    2048
#define D_    2048
#define H_    32
#define KVH_  4
#define HD_   64
#define QKVN  2560   // H*HD + 2*KVH*HD

typedef __bf16 bf16_t;
typedef __bf16 bf16x8 __attribute__((ext_vector_type(8)));
typedef __bf16 bf16x4 __attribute__((ext_vector_type(4)));
typedef float  f32x4  __attribute__((ext_vector_type(4)));

// ---------- fp32 -> bf16 convert (4 elems/thread) ----------
__global__ __launch_bounds__(256) void cvt_bf16_k(const float* __restrict__ in,
                                                  bf16_t* __restrict__ out, int n4) {
  int i = blockIdx.x * 256 + threadIdx.x;
  if (i >= n4) return;
  float4 v = ((const float4*)in)[i];
  bf16x4 o = { (bf16_t)v.x, (bf16_t)v.y, (bf16_t)v.z, (bf16_t)v.w };
  ((bf16x4*)out)[i] = o;
}

// ---------- transpose (K x N) fp32 -> (N x K) bf16 ----------
__global__ __launch_bounds__(256) void transpose_cvt_k(const float* __restrict__ src,
                                                       bf16_t* __restrict__ dst,
                                                       int K, int N) {
  __shared__ float tile[32][33];
  int kb = blockIdx.x * 32, nb = blockIdx.y * 32;
  int tx = threadIdx.x & 31, ty = threadIdx.x >> 5;  // 32 x 8 threads
  #pragma unroll
  for (int i = ty; i < 32; i += 8)
    tile[i][tx] = src[(long)(kb + i) * N + (nb + tx)];
  __syncthreads();
  #pragma unroll
  for (int i = ty; i < 32; i += 8)
    dst[(long)(nb + i) * K + (kb + tx)] = (bf16_t)tile[tx][i];
}

// ---------- bf16 MFMA GEMM: C[M][N] = A[M][K] * Bt[N][K]^T (fp32 out) ----------
// m92-verified layout: a_frag = A[m=lane&15][k=quad*8+j]; b_frag = Bt[n=lane&15][k=quad*8+j];
// C/D: col = lane&15, row = quad*4 + reg.
__global__ __launch_bounds__(256) void gemm_bt_k(const bf16_t* __restrict__ A,
                                                 const bf16_t* __restrict__ Bt,
                                                 float* __restrict__ C,
                                                 int M, int N, int K) {
  __shared__ bf16_t As[64][32];
  __shared__ bf16_t Bs[64][32];
  int m0 = blockIdx.x * 64, n0 = blockIdx.y * 64;
  int tid  = threadIdx.x;
  int wave = tid >> 6, lane = tid & 63;
  int lrow = lane & 15, lquad = lane >> 4;
  f32x4 acc0 = {0,0,0,0}, acc1 = {0,0,0,0}, acc2 = {0,0,0,0}, acc3 = {0,0,0,0};
  int srow = tid >> 2;           // 0..63
  int scol = (tid & 3) * 8;      // 0,8,16,24
  const uint4* Ag = (const uint4*)&A[(long)(m0 + srow) * K + scol];
  const uint4* Bg = (const uint4*)&Bt[(long)(n0 + srow) * K + scol];
  uint4* Asp = (uint4*)&As[srow][scol];
  uint4* Bsp = (uint4*)&Bs[srow][scol];

  for (int k0 = 0; k0 < K; k0 += 32) {
    *Asp = Ag[k0 >> 3];          // uint4 = 8 bf16 elems
    *Bsp = Bg[k0 >> 3];
    __syncthreads();
    bf16x8 a  = *(const bf16x8*)&As[wave * 16 + lrow][lquad * 8];
    bf16x8 b0 = *(const bf16x8*)&Bs[ 0 + lrow][lquad * 8];
    bf16x8 b1 = *(const bf16x8*)&Bs[16 + lrow][lquad * 8];
    bf16x8 b2 = *(const bf16x8*)&Bs[32 + lrow][lquad * 8];
    bf16x8 b3 = *(const bf16x8*)&Bs[48 + lrow][lquad * 8];
    acc0 = __builtin_amdgcn_mfma_f32_16x16x32_bf16(a, b0, acc0, 0, 0, 0);
    acc1 = __builtin_amdgcn_mfma_f32_16x16x32_bf16(a, b1, acc1, 0, 0, 0);
    acc2 = __builtin_amdgcn_mfma_f32_16x16x32_bf16(a, b2, acc2, 0, 0, 0);
    acc3 = __builtin_amdgcn_mfma_f32_16x16x32_bf16(a, b3, acc3, 0, 0, 0);
    __syncthreads();
  }

  int crow = m0 + wave * 16 + lquad * 4;
  #pragma unroll
  for (int r = 0; r < 4; r++) {
    long base = (long)(crow + r) * N + n0 + lrow;
    C[base]      = acc0[r];
    C[base + 16] = acc1[r];
    C[base + 32] = acc2[r];
    C[base + 48] = acc3[r];
  }
}

// ---------- RoPE in-place on fp32 QKV buffer ----------
// QKV row m = b*S+s, cols: [0,2048) Q (h*64+d), [2048,2304) K, [2304,2560) V
__global__ __launch_bounds__(256) void rope_k(float* __restrict__ QKV,
                                              const float* __restrict__ freqs) {
  const int PAIRS = (H_ + KVH_) * (HD_ / 2);   // 1152
  int idx = blockIdx.x * 256 + threadIdx.x;
  int row = idx / PAIRS;
  int p   = idx % PAIRS;
  if (row >= B_ * S_) return;
  int s    = row & (S_ - 1);
  int head = p >> 5;        // 0..35
  int j    = p & 31;
  int col  = (head < H_) ? (head * HD_ + 2 * j)
                         : (D_ + (head - H_) * HD_ + 2 * j);
  float2 f = ((const float2*)freqs)[s * 32 + j];   // (cos, sin)
  float2* pq = (float2*)&QKV[(long)row * QKVN + col];
  float2 v = *pq;
  float2 o = { v.x * f.x - v.y * f.y, v.x * f.y + v.y * f.x };
  *pq = o;
}

// ---------- fp32 flash attention, one wave per query row; lane = d ----------
__global__ __launch_bounds__(256) void attn_k(const float* __restrict__ QKV,
                                              bf16_t* __restrict__ attnb) {
  int wave = threadIdx.x >> 6, lane = threadIdx.x & 63;
  int gw = blockIdx.x * 4 + wave;       // 0 .. B*H*S-1
  int q  = gw & (S_ - 1);
  int bh = gw >> 11;
  int h  = bh & (H_ - 1);
  int b  = bh >> 5;
  int kv = h >> 3;                       // GQA: 8 q-heads per kv-head
  const float* base = QKV + (long)b * S_ * QKVN;
  float qd = base[(long)q * QKVN + h * HD_ + lane] * 0.125f;  // 1/sqrt(64)
  const float* Kp = base + D_ + kv * HD_ + lane;
  const float* Vp = base + D_ + KVH_ * HD_ + kv * HD_ + lane;

  float m = -3.0e38f, l = 0.f, o = 0.f;
  for (int k = 0; k <= q; k++) {
    float s = qd * Kp[(long)k * QKVN];
    #pragma unroll
    for (int off = 32; off >= 1; off >>= 1)
      s += __shfl_xor(s, off, 64);
    float vd = Vp[(long)k * QKVN];
    float mn = fmaxf(m, s);
    float scale = __expf(m - mn);
    float pr    = __expf(s - mn);
    l = l * scale + pr;
    o = o * scale + pr * vd;
    m = mn;
  }
  attnb[(long)(b * S_ + q) * D_ + h * HD_ + lane] = (bf16_t)(o / l);
}

extern "C" void kernel_launch(void* const* d_in, const int* in_sizes, int n_in,
                              void* d_out, int out_size, void* d_ws, size_t ws_size,
                              hipStream_t stream) {
  const float* x     = (const float*)d_in[0];
  const float* freqs = (const float*)d_in[1];
  // d_in[2] = mask: causal, implemented analytically
  const float* wq    = (const float*)d_in[3];
  const float* wk    = (const float*)d_in[4];
  const float* wv    = (const float*)d_in[5];
  const float* wo    = (const float*)d_in[6];
  float* out = (float*)d_out;

  // Workspace layout (77.6 MB total):
  //   [0,16M)      xb   : x as bf16 (4096x2048)   -- later reused as attnb
  //   [16M,26.5M)  wcat : [wq^T; wk^T; wv^T] bf16 (2560x2048)
  //   [26.5M,35M)  woT  : wo^T bf16 (2048x2048)
  //   [35M,77.6M)  QKV  : fp32 (4096x2560)
  char* ws = (char*)d_ws;
  bf16_t* xb    = (bf16_t*)(ws);
  bf16_t* wcat  = (bf16_t*)(ws + 16777216);
  bf16_t* woT   = (bf16_t*)(ws + 27262976);
  float*  QKV   = (float*) (ws + 35651584);
  bf16_t* attnb = xb;   // xb dead after QKV GEMM; reuse for attention output

  // 1) convert x to bf16
  cvt_bf16_k<<<8192, 256, 0, stream>>>(x, xb, 2097152);

  // 2) transpose+convert weights: wcat rows [0,2048)=wq^T, [2048,2304)=wk^T, [2304,2560)=wv^T
  {
    dim3 g(64, 64); transpose_cvt_k<<<g, 256, 0, stream>>>(wq, wcat, 2048, 2048);
  }
  {
    dim3 g(64, 8);
    transpose_cvt_k<<<g, 256, 0, stream>>>(wk, wcat + (long)2048 * 2048, 2048, 256);
    transpose_cvt_k<<<g, 256, 0, stream>>>(wv, wcat + (long)2304 * 2048, 2048, 256);
  }
  {
    dim3 g(64, 64); transpose_cvt_k<<<g, 256, 0, stream>>>(wo, woT, 2048, 2048);
  }

  // 3) fused QKV projection: QKV[4096][2560] = xb @ wcat^T
  {
    dim3 g(64, 40); gemm_bt_k<<<g, 256, 0, stream>>>(xb, wcat, QKV, 4096, QKVN, 2048);
  }

  // 4) RoPE on Q and K in place
  rope_k<<<18432, 256, 0, stream>>>(QKV, freqs);

  // 5) causal GQA attention -> attnb bf16 (4096x2048)
  attn_k<<<32768, 256, 0, stream>>>(QKV, attnb);

  // 6) output projection: out[4096][2048] = attnb @ woT^T
  {
    dim3 g(64, 32); gemm_bt_k<<<g, 256, 0, stream>>>(attnb, woT, out, 4096, 2048, 2048);
  }
}

// Round 2
// 654.684 us; speedup vs baseline: 14.1439x; 14.1439x over previous
//
#include <hip/hip_runtime.h>
#include <hip/hip_bf16.h>

// Problem constants
#define B_    2
#define S_    2048
#define D_    2048
#define H_    32
#define KVH_  4
#define HD_   64
#define QKVN  2560   // H*HD + 2*KVH*HD

typedef __bf16 bf16_t;
typedef __bf16 bf16x8 __attribute__((ext_vector_type(8)));
typedef __bf16 bf16x4 __attribute__((ext_vector_type(4)));
typedef __bf16 bf16x2 __attribute__((ext_vector_type(2)));
typedef float  f32x4  __attribute__((ext_vector_type(4)));

// ---------- fp32 -> bf16 convert (4 elems/thread) ----------
__global__ __launch_bounds__(256) void cvt_bf16_k(const float* __restrict__ in,
                                                  bf16_t* __restrict__ out, int n4) {
  int i = blockIdx.x * 256 + threadIdx.x;
  if (i >= n4) return;
  float4 v = ((const float4*)in)[i];
  bf16x4 o = { (bf16_t)v.x, (bf16_t)v.y, (bf16_t)v.z, (bf16_t)v.w };
  ((bf16x4*)out)[i] = o;
}

// ---------- transpose (K x N) fp32 -> (N x K) bf16 ----------
__global__ __launch_bounds__(256) void transpose_cvt_k(const float* __restrict__ src,
                                                       bf16_t* __restrict__ dst,
                                                       int K, int N) {
  __shared__ float tile[32][33];
  int kb = blockIdx.x * 32, nb = blockIdx.y * 32;
  int tx = threadIdx.x & 31, ty = threadIdx.x >> 5;  // 32 x 8 threads
  #pragma unroll
  for (int i = ty; i < 32; i += 8)
    tile[i][tx] = src[(long)(kb + i) * N + (nb + tx)];
  __syncthreads();
  #pragma unroll
  for (int i = ty; i < 32; i += 8)
    dst[(long)(nb + i) * K + (kb + tx)] = (bf16_t)tile[tx][i];
}

// ---------- bf16 MFMA GEMM: C[M][N] = A[M][K] * Bt[N][K]^T (fp32 out) ----------
__global__ __launch_bounds__(256) void gemm_bt_k(const bf16_t* __restrict__ A,
                                                 const bf16_t* __restrict__ Bt,
                                                 float* __restrict__ C,
                                                 int M, int N, int K) {
  __shared__ bf16_t As[64][32];
  __shared__ bf16_t Bs[64][32];
  int m0 = blockIdx.x * 64, n0 = blockIdx.y * 64;
  int tid  = threadIdx.x;
  int wave = tid >> 6, lane = tid & 63;
  int lrow = lane & 15, lquad = lane >> 4;
  f32x4 acc0 = {0,0,0,0}, acc1 = {0,0,0,0}, acc2 = {0,0,0,0}, acc3 = {0,0,0,0};
  int srow = tid >> 2;           // 0..63
  int scol = (tid & 3) * 8;      // 0,8,16,24
  const uint4* Ag = (const uint4*)&A[(long)(m0 + srow) * K + scol];
  const uint4* Bg = (const uint4*)&Bt[(long)(n0 + srow) * K + scol];
  uint4* Asp = (uint4*)&As[srow][scol];
  uint4* Bsp = (uint4*)&Bs[srow][scol];

  for (int k0 = 0; k0 < K; k0 += 32) {
    *Asp = Ag[k0 >> 3];          // uint4 = 8 bf16 elems
    *Bsp = Bg[k0 >> 3];
    __syncthreads();
    bf16x8 a  = *(const bf16x8*)&As[wave * 16 + lrow][lquad * 8];
    bf16x8 b0 = *(const bf16x8*)&Bs[ 0 + lrow][lquad * 8];
    bf16x8 b1 = *(const bf16x8*)&Bs[16 + lrow][lquad * 8];
    bf16x8 b2 = *(const bf16x8*)&Bs[32 + lrow][lquad * 8];
    bf16x8 b3 = *(const bf16x8*)&Bs[48 + lrow][lquad * 8];
    acc0 = __builtin_amdgcn_mfma_f32_16x16x32_bf16(a, b0, acc0, 0, 0, 0);
    acc1 = __builtin_amdgcn_mfma_f32_16x16x32_bf16(a, b1, acc1, 0, 0, 0);
    acc2 = __builtin_amdgcn_mfma_f32_16x16x32_bf16(a, b2, acc2, 0, 0, 0);
    acc3 = __builtin_amdgcn_mfma_f32_16x16x32_bf16(a, b3, acc3, 0, 0, 0);
    __syncthreads();
  }

  int crow = m0 + wave * 16 + lquad * 4;
  #pragma unroll
  for (int r = 0; r < 4; r++) {
    long base = (long)(crow + r) * N + n0 + lrow;
    C[base]      = acc0[r];
    C[base + 16] = acc1[r];
    C[base + 32] = acc2[r];
    C[base + 48] = acc3[r];
  }
}

// ---------- RoPE + repack Q,K to bf16 head-major layouts ----------
// Qb[((b*H+h)*S+s)*64 + d]  (scaled by 1/8, lossless pow2)
// Kb[((b*KVH+kv)*S+s)*64 + d]
__global__ __launch_bounds__(256) void ropepack_k(const float* __restrict__ QKV,
                                                  const float* __restrict__ freqs,
                                                  bf16_t* __restrict__ Qb,
                                                  bf16_t* __restrict__ Kb) {
  const int PAIRS = (H_ + KVH_) * (HD_ / 2);   // 1152
  int idx = blockIdx.x * 256 + threadIdx.x;
  int row = idx / PAIRS;
  int p   = idx % PAIRS;
  if (row >= B_ * S_) return;
  int s    = row & (S_ - 1);
  int b    = row >> 11;
  int head = p >> 5;        // 0..35 (0..31 = Q heads, 32..35 = K heads)
  int j    = p & 31;
  float2 f = ((const float2*)freqs)[s * 32 + j];   // (cos, sin)
  int col = (head < H_) ? (head * HD_ + 2 * j)
                        : (D_ + (head - H_) * HD_ + 2 * j);
  float2 v = *(const float2*)&QKV[(long)row * QKVN + col];
  float2 o = { v.x * f.x - v.y * f.y, v.x * f.y + v.y * f.x };
  if (head < H_) {
    o.x *= 0.125f; o.y *= 0.125f;   // fold 1/sqrt(HD) into Q
    bf16x2 w = { (bf16_t)o.x, (bf16_t)o.y };
    *(bf16x2*)&Qb[(((long)(b * H_ + head) * S_ + s) * HD_) + 2 * j] = w;
  } else {
    bf16x2 w = { (bf16_t)o.x, (bf16_t)o.y };
    *(bf16x2*)&Kb[(((long)(b * KVH_ + (head - H_)) * S_ + s) * HD_) + 2 * j] = w;
  }
}

// ---------- V transpose: QKV fp32 -> Vt bf16 [(b*KVH+kv)*64 + d][S] ----------
__global__ __launch_bounds__(256) void vtrans_k(const float* __restrict__ QKV,
                                                bf16_t* __restrict__ Vt) {
  __shared__ float tile[32][33];
  int s0 = blockIdx.x * 32, d0 = blockIdx.y * 32, bkv = blockIdx.z;  // bkv 0..7
  int b = bkv >> 2, kv = bkv & 3;
  int tx = threadIdx.x & 31, ty = threadIdx.x >> 5;
  const float* src = QKV + (long)b * S_ * QKVN + D_ + KVH_ * HD_ + kv * HD_;
  #pragma unroll
  for (int i = ty; i < 32; i += 8)
    tile[i][tx] = src[(long)(s0 + i) * QKVN + d0 + tx];
  __syncthreads();
  #pragma unroll
  for (int i = ty; i < 32; i += 8)
    Vt[((long)bkv * HD_ + d0 + i) * S_ + s0 + tx] = (bf16_t)tile[tx][i];
}

#define MFMA16(a, b, c) __builtin_amdgcn_mfma_f32_16x16x32_bf16(a, b, c, 0, 0, 0)

// ---------- MFMA flash attention ----------
// block = (q-tile of 64, b*H+h); 4 waves x 16 queries; 32-key tiles.
__global__ __launch_bounds__(256) void fattn_k(const bf16_t* __restrict__ Qb,
                                               const bf16_t* __restrict__ Kb,
                                               const bf16_t* __restrict__ Vt,
                                               bf16_t* __restrict__ attnb) {
  __shared__ bf16_t Qs[64][72];       // +8 pad: 16B-aligned b128 rows, 2-way banks
  __shared__ bf16_t Ks[32][72];
  __shared__ bf16_t Vts[64][40];      // [dim][key] (+8 pad)
  __shared__ bf16_t Pl[4][16][40];    // per-wave P round-trip

  int q0 = blockIdx.x * 64;
  int bh = blockIdx.y;                // 0..63
  int b = bh >> 5, h = bh & (H_ - 1), kv = h >> 3;
  int tid = threadIdx.x, wave = tid >> 6, lane = tid & 63;
  int lrow = lane & 15, quad = lane >> 4;

  // stage Q tile 64x64 (2 uint4 per thread)
  {
    const uint4* src = (const uint4*)(Qb + ((long)bh * S_ + q0) * HD_);
    int r = tid >> 2, c = tid & 3;
    uint4 v0 = src[r * 8 + c];
    uint4 v1 = src[r * 8 + c + 4];
    *(uint4*)&Qs[r][c * 8]      = v0;
    *(uint4*)&Qs[r][c * 8 + 32] = v1;
  }
  __syncthreads();
  bf16x8 a0 = *(const bf16x8*)&Qs[wave * 16 + lrow][quad * 8];
  bf16x8 a1 = *(const bf16x8*)&Qs[wave * 16 + lrow][32 + quad * 8];

  f32x4 o0 = {0,0,0,0}, o1 = {0,0,0,0}, o2 = {0,0,0,0}, o3 = {0,0,0,0};
  float m[4] = {-1e30f,-1e30f,-1e30f,-1e30f}, l[4] = {0.f,0.f,0.f,0.f};

  const uint4* Kg = (const uint4*)(Kb + (long)(b * KVH_ + kv) * S_ * HD_);
  const uint4* Vg = (const uint4*)(Vt + (long)(b * KVH_ + kv) * HD_ * S_);
  int qw = q0 + wave * 16;            // wave's min query
  int qbase = qw + quad * 4;          // this lane's query rows: qbase..qbase+3

  int nt = (q0 >> 5) + 2;             // key tiles covering [0, q0+63]
  for (int kt = 0; kt < nt; kt++) {
    int k0 = kt * 32;
    // stage K tile 32x64 (1 uint4/thread)
    { int r = tid >> 3, c = tid & 7;
      uint4 v = Kg[(k0 + r) * 8 + c];
      *(uint4*)&Ks[r][c * 8] = v; }
    // stage Vt tile 64 dims x 32 keys (1 uint4/thread); global row = 256 uint4
    { int d = tid >> 2, c = tid & 3;
      uint4 v = Vg[(long)d * 256 + (k0 >> 3) + c];
      *(uint4*)&Vts[d][c * 8] = v; }
    __syncthreads();

    if (k0 <= qw + 15) {              // skip fully-masked tiles for this wave
      // S = Q K^T  (16 queries x 32 keys)
      bf16x8 bk00 = *(const bf16x8*)&Ks[lrow][quad * 8];
      bf16x8 bk01 = *(const bf16x8*)&Ks[lrow][32 + quad * 8];
      bf16x8 bk10 = *(const bf16x8*)&Ks[16 + lrow][quad * 8];
      bf16x8 bk11 = *(const bf16x8*)&Ks[16 + lrow][32 + quad * 8];
      f32x4 s0 = {0,0,0,0}, s1 = {0,0,0,0};
      s0 = MFMA16(a0, bk00, s0); s0 = MFMA16(a1, bk01, s0);
      s1 = MFMA16(a0, bk10, s1); s1 = MFMA16(a1, bk11, s1);

      if (k0 + 31 > qw) {             // diagonal tile: causal mask
        int key0 = k0 + lrow, key1 = key0 + 16;
        #pragma unroll
        for (int r = 0; r < 4; r++) {
          int qq = qbase + r;
          if (key0 > qq) s0[r] = -1e30f;
          if (key1 > qq) s1[r] = -1e30f;
        }
      }

      // online softmax (rows distributed: row = quad*4+r, 16 key-lanes)
      float p0[4], p1[4];
      #pragma unroll
      for (int r = 0; r < 4; r++) {
        float t = fmaxf(s0[r], s1[r]);
        #pragma unroll
        for (int off = 8; off >= 1; off >>= 1) t = fmaxf(t, __shfl_xor(t, off, 64));
        float mn = fmaxf(m[r], t);
        float al = __expf(m[r] - mn);
        p0[r] = __expf(s0[r] - mn);
        p1[r] = __expf(s1[r] - mn);
        float rs = p0[r] + p1[r];
        #pragma unroll
        for (int off = 8; off >= 1; off >>= 1) rs += __shfl_xor(rs, off, 64);
        l[r] = l[r] * al + rs;
        m[r] = mn;
        o0[r] *= al; o1[r] *= al; o2[r] *= al; o3[r] *= al;
      }

      // P: C/D layout -> LDS -> A layout (per-wave region, no barrier needed)
      #pragma unroll
      for (int r = 0; r < 4; r++) {
        Pl[wave][quad * 4 + r][lrow]      = (bf16_t)p0[r];
        Pl[wave][quad * 4 + r][16 + lrow] = (bf16_t)p1[r];
      }
      bf16x8 pa  = *(const bf16x8*)&Pl[wave][lrow][quad * 8];
      bf16x8 vb0 = *(const bf16x8*)&Vts[     lrow][quad * 8];
      bf16x8 vb1 = *(const bf16x8*)&Vts[16 + lrow][quad * 8];
      bf16x8 vb2 = *(const bf16x8*)&Vts[32 + lrow][quad * 8];
      bf16x8 vb3 = *(const bf16x8*)&Vts[48 + lrow][quad * 8];
      o0 = MFMA16(pa, vb0, o0);
      o1 = MFMA16(pa, vb1, o1);
      o2 = MFMA16(pa, vb2, o2);
      o3 = MFMA16(pa, vb3, o3);
    }
    __syncthreads();
  }

  // epilogue: divide by l, store bf16 to attnb[(b*S+q)*D + h*64 + d]
  #pragma unroll
  for (int r = 0; r < 4; r++) {
    float inv = 1.f / l[r];
    int qq = qbase + r;
    long base = ((long)(b * S_ + qq)) * D_ + h * HD_ + lrow;
    attnb[base]      = (bf16_t)(o0[r] * inv);
    attnb[base + 16] = (bf16_t)(o1[r] * inv);
    attnb[base + 32] = (bf16_t)(o2[r] * inv);
    attnb[base + 48] = (bf16_t)(o3[r] * inv);
  }
}

extern "C" void kernel_launch(void* const* d_in, const int* in_sizes, int n_in,
                              void* d_out, int out_size, void* d_ws, size_t ws_size,
                              hipStream_t stream) {
  const float* x     = (const float*)d_in[0];
  const float* freqs = (const float*)d_in[1];
  // d_in[2] = mask: causal, implemented analytically
  const float* wq    = (const float*)d_in[3];
  const float* wk    = (const float*)d_in[4];
  const float* wv    = (const float*)d_in[5];
  const float* wo    = (const float*)d_in[6];
  float* out = (float*)d_out;

  // Workspace layout (77.6 MB), with lifetime-based aliasing:
  //   [0,16.8M)       xb (bf16 x)            -> later Qb (same size)
  //   [16.8M,27.3M)   wcat (qkv weights^T)   -> later Kb (2MB) + Vt (2MB)
  //   [27.3M,35.7M)   woT
  //   [35.7M,77.6M)   QKV fp32               -> later attnb (16.8MB)
  char* ws = (char*)d_ws;
  bf16_t* xb    = (bf16_t*)(ws);
  bf16_t* wcat  = (bf16_t*)(ws + 16777216);
  bf16_t* woT   = (bf16_t*)(ws + 27262976);
  float*  QKV   = (float*) (ws + 35651584);
  bf16_t* Qb    = xb;                         // xb dead after QKV GEMM
  bf16_t* Kb    = (bf16_t*)(ws + 16777216);   // wcat dead after QKV GEMM
  bf16_t* Vt    = (bf16_t*)(ws + 18874368);
  bf16_t* attnb = (bf16_t*)(ws + 35651584);   // QKV dead after repack

  // 1) convert x to bf16
  cvt_bf16_k<<<8192, 256, 0, stream>>>(x, xb, 2097152);

  // 2) transpose+convert weights
  { dim3 g(64, 64); transpose_cvt_k<<<g, 256, 0, stream>>>(wq, wcat, 2048, 2048); }
  { dim3 g(64, 8);
    transpose_cvt_k<<<g, 256, 0, stream>>>(wk, wcat + (long)2048 * 2048, 2048, 256);
    transpose_cvt_k<<<g, 256, 0, stream>>>(wv, wcat + (long)2304 * 2048, 2048, 256); }
  { dim3 g(64, 64); transpose_cvt_k<<<g, 256, 0, stream>>>(wo, woT, 2048, 2048); }

  // 3) fused QKV projection: QKV[4096][2560] = xb @ wcat^T
  { dim3 g(64, 40); gemm_bt_k<<<g, 256, 0, stream>>>(xb, wcat, QKV, 4096, QKVN, 2048); }

  // 4) RoPE + repack Q,K (bf16, head-major); transpose V
  ropepack_k<<<18432, 256, 0, stream>>>(QKV, freqs, Qb, Kb);
  { dim3 g(64, 2, 8); vtrans_k<<<g, 256, 0, stream>>>(QKV, Vt); }

  // 5) MFMA flash attention -> attnb bf16 (4096x2048)
  { dim3 g(32, 64); fattn_k<<<g, 256, 0, stream>>>(Qb, Kb, Vt, attnb); }

  // 6) output projection: out[4096][2048] = attnb @ woT^T
  { dim3 g(64, 32); gemm_bt_k<<<g, 256, 0, stream>>>(attnb, woT, out, 4096, 2048, 2048); }
}

// Round 3
// 438.236 us; speedup vs baseline: 21.1296x; 1.4939x over previous
//
#include <hip/hip_runtime.h>
#include <hip/hip_bf16.h>
#include <stdint.h>

// Problem constants
#define B_    2
#define S_    2048
#define D_    2048
#define H_    32
#define KVH_  4
#define HD_   64
#define QKVN  2560   // H*HD + 2*KVH*HD

typedef __bf16 bf16_t;
typedef __bf16 bf16x8 __attribute__((ext_vector_type(8)));
typedef __bf16 bf16x4 __attribute__((ext_vector_type(4)));
typedef __bf16 bf16x2 __attribute__((ext_vector_type(2)));
typedef float  f32x4  __attribute__((ext_vector_type(4)));

#define MFMA16(a, b, c) __builtin_amdgcn_mfma_f32_16x16x32_bf16(a, b, c, 0, 0, 0)

// async global->LDS, 16B per lane. LDS dest must be wave-uniform base + lane*16
// (lane-affine pointers OK). Generic->AS3 via 32-bit truncation (LDS aperture
// is 4GiB-aligned, low 32 bits = LDS offset).
__device__ __forceinline__ void gld16(const void* g, void* l) {
  __builtin_amdgcn_global_load_lds(
      (const __attribute__((address_space(1))) uint32_t*)(uintptr_t)g,
      (__attribute__((address_space(3))) uint32_t*)(uint32_t)(uintptr_t)l,
      16, 0, 0);
}

// ---------- fp32 -> bf16 convert (4 elems/thread) ----------
__global__ __launch_bounds__(256) void cvt_bf16_k(const float* __restrict__ in,
                                                  bf16_t* __restrict__ out, int n4) {
  int i = blockIdx.x * 256 + threadIdx.x;
  if (i >= n4) return;
  float4 v = ((const float4*)in)[i];
  bf16x4 o = { (bf16_t)v.x, (bf16_t)v.y, (bf16_t)v.z, (bf16_t)v.w };
  ((bf16x4*)out)[i] = o;
}

// ---------- transpose (K x N) fp32 -> (N x K) bf16 ----------
__global__ __launch_bounds__(256) void transpose_cvt_k(const float* __restrict__ src,
                                                       bf16_t* __restrict__ dst,
                                                       int K, int N) {
  __shared__ float tile[32][33];
  int kb = blockIdx.x * 32, nb = blockIdx.y * 32;
  int tx = threadIdx.x & 31, ty = threadIdx.x >> 5;  // 32 x 8 threads
  #pragma unroll
  for (int i = ty; i < 32; i += 8)
    tile[i][tx] = src[(long)(kb + i) * N + (nb + tx)];
  __syncthreads();
  #pragma unroll
  for (int i = ty; i < 32; i += 8)
    dst[(long)(nb + i) * K + (kb + tx)] = (bf16_t)tile[tx][i];
}

// ---------- m97-style 128x128 MFMA GEMM: C[M][N] = A[M][K] * Bt[N][K]^T ----------
// global_load_lds width-16 staging, XOR chunk-swizzle on global side so frag
// ds_read_b128 hits all 32 banks. 4 waves in 2x2; 16 MFMA + 8 b128 per K-step.
__global__ __launch_bounds__(256) void gemm128_k(const bf16_t* __restrict__ A,
                                                 const bf16_t* __restrict__ Bt,
                                                 float* __restrict__ C,
                                                 int M, int N, int K) {
  __shared__ bf16_t As[128 * 32];
  __shared__ bf16_t Bs[128 * 32];
  const int tid = threadIdx.x, lane = tid & 63;
  const int wave = tid >> 6, wr = wave >> 1, wc = wave & 1;
  const int lrow = lane & 15, quad = lane >> 4;
  const long m0 = (long)blockIdx.x * 128, n0 = (long)blockIdx.y * 128;

  f32x4 acc[4][4];
  #pragma unroll
  for (int i = 0; i < 4; i++)
    #pragma unroll
    for (int j = 0; j < 4; j++) acc[i][j] = (f32x4){0.f, 0.f, 0.f, 0.f};

  // staging: slot idx (0..511) holds global chunk (row=idx>>2, c=(idx&3)^(row&3))
  const int r0 = tid >> 2;
  const int cg = ((tid & 3) ^ (r0 & 3)) * 8;
  const bf16_t* Ag0 = A  + (m0 + r0) * (long)K + cg;
  const bf16_t* Ag1 = Ag0 + 64 * (long)K;
  const bf16_t* Bg0 = Bt + (n0 + r0) * (long)K + cg;
  const bf16_t* Bg1 = Bg0 + 64 * (long)K;
  bf16_t* As0 = As + tid * 8; bf16_t* As1 = As0 + 2048;
  bf16_t* Bs0 = Bs + tid * 8; bf16_t* Bs1 = Bs0 + 2048;
  const int swz = (quad ^ (lrow & 3)) * 8;   // frag chunk swizzle

  for (int k0 = 0; k0 < K; k0 += 32) {
    gld16(Ag0 + k0, As0);
    gld16(Ag1 + k0, As1);
    gld16(Bg0 + k0, Bs0);
    gld16(Bg1 + k0, Bs1);
    __syncthreads();
    bf16x8 af[4], bfr[4];
    #pragma unroll
    for (int i = 0; i < 4; i++)
      af[i] = *(const bf16x8*)&As[(wr * 64 + i * 16 + lrow) * 32 + swz];
    #pragma unroll
    for (int j = 0; j < 4; j++)
      bfr[j] = *(const bf16x8*)&Bs[(wc * 64 + j * 16 + lrow) * 32 + swz];
    #pragma unroll
    for (int i = 0; i < 4; i++)
      #pragma unroll
      for (int j = 0; j < 4; j++)
        acc[i][j] = MFMA16(af[i], bfr[j], acc[i][j]);
    __syncthreads();
  }

  #pragma unroll
  for (int i = 0; i < 4; i++) {
    #pragma unroll
    for (int r = 0; r < 4; r++) {
      long row = m0 + wr * 64 + i * 16 + quad * 4 + r;
      float* cp = C + row * N + n0 + wc * 64 + lrow;
      #pragma unroll
      for (int j = 0; j < 4; j++) cp[j * 16] = acc[i][j][r];
    }
  }
}

// ---------- RoPE + repack Q,K to bf16 head-major layouts ----------
// Qb[((b*H+h)*S+s)*64+d] scaled by (1/8)*log2(e) so attention can use exp2.
// Kb[((b*KVH+kv)*S+s)*64+d]
__global__ __launch_bounds__(256) void ropepack_k(const float* __restrict__ QKV,
                                                  const float* __restrict__ freqs,
                                                  bf16_t* __restrict__ Qb,
                                                  bf16_t* __restrict__ Kb) {
  const int PAIRS = (H_ + KVH_) * (HD_ / 2);   // 1152
  int idx = blockIdx.x * 256 + threadIdx.x;
  int row = idx / PAIRS;
  int p   = idx % PAIRS;
  if (row >= B_ * S_) return;
  int s    = row & (S_ - 1);
  int b    = row >> 11;
  int head = p >> 5;        // 0..35 (0..31 = Q heads, 32..35 = K heads)
  int j    = p & 31;
  float2 f = ((const float2*)freqs)[s * 32 + j];   // (cos, sin)
  int col = (head < H_) ? (head * HD_ + 2 * j)
                        : (D_ + (head - H_) * HD_ + 2 * j);
  float2 v = *(const float2*)&QKV[(long)row * QKVN + col];
  float2 o = { v.x * f.x - v.y * f.y, v.x * f.y + v.y * f.x };
  if (head < H_) {
    const float qs = 0.125f * 1.4426950408889634f;  // 1/sqrt(64) * log2(e)
    o.x *= qs; o.y *= qs;
    bf16x2 w = { (bf16_t)o.x, (bf16_t)o.y };
    *(bf16x2*)&Qb[(((long)(b * H_ + head) * S_ + s) * HD_) + 2 * j] = w;
  } else {
    bf16x2 w = { (bf16_t)o.x, (bf16_t)o.y };
    *(bf16x2*)&Kb[(((long)(b * KVH_ + (head - H_)) * S_ + s) * HD_) + 2 * j] = w;
  }
}

// ---------- V transpose: QKV fp32 -> Vt bf16 [(b*KVH+kv)*64 + d][S] ----------
__global__ __launch_bounds__(256) void vtrans_k(const float* __restrict__ QKV,
                                                bf16_t* __restrict__ Vt) {
  __shared__ float tile[32][33];
  int s0 = blockIdx.x * 32, d0 = blockIdx.y * 32, bkv = blockIdx.z;  // bkv 0..7
  int b = bkv >> 2, kv = bkv & 3;
  int tx = threadIdx.x & 31, ty = threadIdx.x >> 5;
  const float* src = QKV + (long)b * S_ * QKVN + D_ + KVH_ * HD_ + kv * HD_;
  #pragma unroll
  for (int i = ty; i < 32; i += 8)
    tile[i][tx] = src[(long)(s0 + i) * QKVN + d0 + tx];
  __syncthreads();
  #pragma unroll
  for (int i = ty; i < 32; i += 8)
    Vt[((long)bkv * HD_ + d0 + i) * S_ + s0 + tx] = (bf16_t)tile[tx][i];
}

// ---------- MFMA flash attention, transposed (S^T = K Q^T, O^T = V^T P^T) ----------
// block = (64-query tile, b*H+h); 4 waves x 16 queries; 64-key LDS tiles.
// Lane (quad,lrow): owns query qw+lrow; holds 4 keys per 16-key sub-tile.
__global__ __launch_bounds__(256) void fattn_k(const bf16_t* __restrict__ Qb,
                                               const bf16_t* __restrict__ Kb,
                                               const bf16_t* __restrict__ Vt,
                                               bf16_t* __restrict__ attnb) {
  __shared__ bf16_t KQs[64 * 64];     // Q staging (prologue), then K tiles
  __shared__ bf16_t Vts[64 * 64];     // [dim][key]
  __shared__ bf16_t Pt[4][16][72];    // per-wave P^T round-trip [query][key], pad 8

  const int qt = (S_ / 64 - 1) - blockIdx.x;   // heavy q-tiles first
  const int q0 = qt * 64;
  const int bh = blockIdx.y;
  const int b = bh >> 5, h = bh & (H_ - 1), kv = h >> 3;
  const int tid = threadIdx.x, wave = tid >> 6, lane = tid & 63;
  const int lrow = lane & 15, quad = lane >> 4;
  const int qw = q0 + wave * 16;

  const bf16_t* Qg = Qb + ((long)bh * S_ + q0) * HD_;
  const bf16_t* Kg = Kb + (long)(b * KVH_ + kv) * S_ * HD_;
  const bf16_t* Vg = Vt + (long)(b * KVH_ + kv) * HD_ * S_;

  // staging maps: slot idx holds chunk (row=idx>>3, c=(idx&7)^(row&7))
  const int sr  = tid >> 3;                      // 0..31 (+32 on 2nd issue)
  const int scg = ((tid & 7) ^ (sr & 7)) * 8;
  const long qkoff0 = (long)sr * HD_ + scg;
  const long qkoff1 = (long)(sr + 32) * HD_ + scg;
  const long voff0  = (long)sr * S_ + scg;
  const long voff1  = (long)(sr + 32) * S_ + scg;
  bf16_t* lds_lo = KQs + tid * 8;
  bf16_t* lds_hi = KQs + 2048 + tid * 8;
  bf16_t* vlds_lo = Vts + tid * 8;
  bf16_t* vlds_hi = Vts + 2048 + tid * 8;

  // stage Q tile, read B-fragments (wave's 16 queries), then free the buffer
  gld16(Qg + qkoff0, lds_lo);
  gld16(Qg + qkoff1, lds_hi);
  __syncthreads();
  const int sw0 = (quad ^ (lrow & 7)) * 8;   // frag chunk swizzle (dims 0-31)
  const int sw1 = sw0 ^ 32;                  // dims 32-63
  bf16x8 bq0 = *(const bf16x8*)&KQs[(wave * 16 + lrow) * 64 + sw0];
  bf16x8 bq1 = *(const bf16x8*)&KQs[(wave * 16 + lrow) * 64 + sw1];
  __syncthreads();

  f32x4 o[4];
  #pragma unroll
  for (int db = 0; db < 4; db++) o[db] = (f32x4){0.f, 0.f, 0.f, 0.f};
  float mrun = -1e30f, lrun = 0.f;

  const int nt = qt + 1;
  for (int t = 0; t < nt; t++) {
    const long k0 = (long)t * 64;
    gld16(Kg + k0 * HD_ + qkoff0, lds_lo);
    gld16(Kg + k0 * HD_ + qkoff1, lds_hi);
    gld16(Vg + k0 + voff0, vlds_lo);
    gld16(Vg + k0 + voff1, vlds_hi);
    __syncthreads();

    // S^T sub-tiles: 16 keys each; lane r-values = keys kbase+quad*4+r, query qw+lrow
    f32x4 s[4];
    #pragma unroll
    for (int kb = 0; kb < 4; kb++) {
      const int kbase = (int)k0 + kb * 16;
      if (kbase <= qw) {
        bf16x8 ak0 = *(const bf16x8*)&KQs[(kb * 16 + lrow) * 64 + sw0];
        bf16x8 ak1 = *(const bf16x8*)&KQs[(kb * 16 + lrow) * 64 + sw1];
        f32x4 sv = {0.f, 0.f, 0.f, 0.f};
        sv = MFMA16(ak0, bq0, sv);
        sv = MFMA16(ak1, bq1, sv);
        if (kbase == qw) {                    // diagonal sub-tile
          #pragma unroll
          for (int r = 0; r < 4; r++)
            if (quad * 4 + r > lrow) sv[r] = -1e30f;
        }
        s[kb] = sv;
      } else {
        s[kb] = (f32x4){-1e30f, -1e30f, -1e30f, -1e30f};
      }
    }

    // online softmax over 64 keys (scores pre-scaled by log2e/8 -> exp2)
    float tmax = -1e30f;
    #pragma unroll
    for (int kb = 0; kb < 4; kb++)
      #pragma unroll
      for (int r = 0; r < 4; r++) tmax = fmaxf(tmax, s[kb][r]);
    tmax = fmaxf(tmax, __shfl_xor(tmax, 16, 64));
    tmax = fmaxf(tmax, __shfl_xor(tmax, 32, 64));
    const float mn = fmaxf(mrun, tmax);
    const float al = exp2f(mrun - mn);
    float rs = 0.f;
    #pragma unroll
    for (int kb = 0; kb < 4; kb++) {
      bf16x4 pw;
      #pragma unroll
      for (int r = 0; r < 4; r++) {
        const float p = exp2f(s[kb][r] - mn);
        rs += p;
        pw[r] = (bf16_t)p;
      }
      *(bf16x4*)&Pt[wave][lrow][kb * 16 + quad * 4] = pw;   // b64, ~min conflicts
    }
    rs += __shfl_xor(rs, 16, 64);
    rs += __shfl_xor(rs, 32, 64);
    lrun = lrun * al + rs;
    mrun = mn;
    #pragma unroll
    for (int db = 0; db < 4; db++) o[db] *= al;

    // O^T += V^T P^T : A-frag from Vts [dim][key], B-frag from Pt [query][key]
    bf16x8 bp0 = *(const bf16x8*)&Pt[wave][lrow][quad * 8];
    bf16x8 bp1 = *(const bf16x8*)&Pt[wave][lrow][32 + quad * 8];
    #pragma unroll
    for (int db = 0; db < 4; db++) {
      bf16x8 av0 = *(const bf16x8*)&Vts[(db * 16 + lrow) * 64 + sw0];
      bf16x8 av1 = *(const bf16x8*)&Vts[(db * 16 + lrow) * 64 + sw1];
      o[db] = MFMA16(av0, bp0, o[db]);
      o[db] = MFMA16(av1, bp1, o[db]);
    }
    __syncthreads();
  }

  // epilogue: lane holds 16 dims of one query's O^T column
  const float inv = 1.f / lrun;
  const int query = qw + lrow;
  bf16_t* op = attnb + ((long)(b * S_ + query)) * D_ + h * HD_;
  #pragma unroll
  for (int db = 0; db < 4; db++) {
    bf16x4 w = { (bf16_t)(o[db][0] * inv), (bf16_t)(o[db][1] * inv),
                 (bf16_t)(o[db][2] * inv), (bf16_t)(o[db][3] * inv) };
    *(bf16x4*)&op[db * 16 + quad * 4] = w;
  }
}

extern "C" void kernel_launch(void* const* d_in, const int* in_sizes, int n_in,
                              void* d_out, int out_size, void* d_ws, size_t ws_size,
                              hipStream_t stream) {
  const float* x     = (const float*)d_in[0];
  const float* freqs = (const float*)d_in[1];
  // d_in[2] = mask: causal, implemented analytically
  const float* wq    = (const float*)d_in[3];
  const float* wk    = (const float*)d_in[4];
  const float* wv    = (const float*)d_in[5];
  const float* wo    = (const float*)d_in[6];
  float* out = (float*)d_out;

  // Workspace layout (77.6 MB), lifetime-aliased:
  //   [0,16.8M)       xb (bf16 x)            -> later Qb
  //   [16.8M,27.3M)   wcat (qkv weights^T)   -> later Kb (2.1M) + Vt (2.1M)
  //   [27.3M,35.7M)   woT
  //   [35.7M,77.6M)   QKV fp32               -> later attnb (16.8M)
  char* ws = (char*)d_ws;
  bf16_t* xb    = (bf16_t*)(ws);
  bf16_t* wcat  = (bf16_t*)(ws + 16777216);
  bf16_t* woT   = (bf16_t*)(ws + 27262976);
  float*  QKV   = (float*) (ws + 35651584);
  bf16_t* Qb    = xb;
  bf16_t* Kb    = (bf16_t*)(ws + 16777216);
  bf16_t* Vt    = (bf16_t*)(ws + 18874368);
  bf16_t* attnb = (bf16_t*)(ws + 35651584);

  // 1) convert x to bf16
  cvt_bf16_k<<<8192, 256, 0, stream>>>(x, xb, 2097152);

  // 2) transpose+convert weights
  { dim3 g(64, 64); transpose_cvt_k<<<g, 256, 0, stream>>>(wq, wcat, 2048, 2048); }
  { dim3 g(64, 8);
    transpose_cvt_k<<<g, 256, 0, stream>>>(wk, wcat + (long)2048 * 2048, 2048, 256);
    transpose_cvt_k<<<g, 256, 0, stream>>>(wv, wcat + (long)2304 * 2048, 2048, 256); }
  { dim3 g(64, 64); transpose_cvt_k<<<g, 256, 0, stream>>>(wo, woT, 2048, 2048); }

  // 3) fused QKV projection: QKV[4096][2560] = xb @ wcat^T
  { dim3 g(32, 20); gemm128_k<<<g, 256, 0, stream>>>(xb, wcat, QKV, 4096, QKVN, 2048); }

  // 4) RoPE + repack Q,K (bf16, head-major, exp2-prescaled Q); transpose V
  ropepack_k<<<18432, 256, 0, stream>>>(QKV, freqs, Qb, Kb);
  { dim3 g(64, 2, 8); vtrans_k<<<g, 256, 0, stream>>>(QKV, Vt); }

  // 5) MFMA flash attention -> attnb bf16 (4096x2048)
  { dim3 g(32, 64); fattn_k<<<g, 256, 0, stream>>>(Qb, Kb, Vt, attnb); }

  // 6) output projection: out[4096][2048] = attnb @ woT^T
  { dim3 g(32, 16); gemm128_k<<<g, 256, 0, stream>>>(attnb, woT, out, 4096, 2048, 2048); }
}